// Round 11
// baseline (363.887 us; speedup 1.0000x reference)
//
#include <hip/hip_runtime.h>
#include <math.h>

#define N_NODES 100000
#define NE      1200000
#define D       64
#define H2      32
#define BN_EPS  1e-5f
#define SCAN_B  512

// bucket sort parameters
#define BSHIFT  9
#define BNODES  512                      // nodes per coarse bucket
#define NBUK    256                      // bucket slots (used: 196)
#define NBUK_USED ((N_NODES + BNODES - 1) / BNODES)   // 196
#define NB1     256                      // pass-1 blocks
#define EPB1    ((NE + NB1 - 1) / NB1)   // 4688 edges per pass-1 block
#define NSCAN   (NBUK * NB1)             // 65536 scan entries
#define SRC_BITS 17
#define SRC_MASK ((1 << SRC_BITS) - 1)

typedef short bf16x8 __attribute__((ext_vector_type(8)));
typedef float f32x4 __attribute__((ext_vector_type(4)));

// ---- bf16 helpers (RNE) ----------------------------------------------------
__device__ __forceinline__ unsigned short f2bf(float f) {
  unsigned int u = __float_as_uint(f);
  u += 0x7fffu + ((u >> 16) & 1u);
  return (unsigned short)(u >> 16);
}
__device__ __forceinline__ float bflo(unsigned int u) { return __uint_as_float(u << 16); }
__device__ __forceinline__ float bfhi(unsigned int u) { return __uint_as_float(u & 0xffff0000u); }
__device__ __forceinline__ unsigned int pack2(float lo, float hi) {
  return (unsigned int)f2bf(lo) | ((unsigned int)f2bf(hi) << 16);
}

__device__ __forceinline__ bf16x8 ldw(const float* p) {
  float4 w0 = *reinterpret_cast<const float4*>(p);
  float4 w1 = *reinterpret_cast<const float4*>(p + 4);
  bf16x8 b;
  b[0] = (short)f2bf(w0.x); b[1] = (short)f2bf(w0.y);
  b[2] = (short)f2bf(w0.z); b[3] = (short)f2bf(w0.w);
  b[4] = (short)f2bf(w1.x); b[5] = (short)f2bf(w1.y);
  b[6] = (short)f2bf(w1.z); b[7] = (short)f2bf(w1.w);
  return b;
}

// ---------------------------------------------------------------------------
// Pass 1a: per-block LDS histogram of coarse buckets (dst>>9); also converts
// x (f32) -> xh (bf16). All atomics are LDS.
// ---------------------------------------------------------------------------
__global__ __launch_bounds__(256) void bucket_hist_kernel(
    const int* __restrict__ dst, int* __restrict__ bhist,
    const float* __restrict__ x, unsigned short* __restrict__ xh) {
  __shared__ int h[NBUK];
  int tid = threadIdx.x;
  h[tid] = 0;
  __syncthreads();
  int e0 = blockIdx.x * EPB1;
  int e1 = e0 + EPB1; if (e1 > NE) e1 = NE;
  for (int e = e0 + tid; e < e1; e += 256)
    atomicAdd(&h[dst[e] >> BSHIFT], 1);
  __syncthreads();
  bhist[tid * NB1 + blockIdx.x] = h[tid];

  const int nquads = N_NODES * D / 4;
  for (int i = blockIdx.x * 256 + tid; i < nquads; i += NB1 * 256) {
    float4 v = reinterpret_cast<const float4*>(x)[i];
    ushort4 o;
    o.x = f2bf(v.x); o.y = f2bf(v.y); o.z = f2bf(v.z); o.w = f2bf(v.w);
    reinterpret_cast<ushort4*>(xh)[i] = o;
  }
}

// ---------------------------------------------------------------------------
// Blocked inclusive scan over bhist[0..NSCAN).
// ---------------------------------------------------------------------------
__global__ __launch_bounds__(SCAN_B) void scan_part(int* __restrict__ a,
                                                    int* __restrict__ bsum, int n) {
  __shared__ int s[SCAN_B];
  int i = blockIdx.x * SCAN_B + threadIdx.x;
  int v = (i < n) ? a[i] : 0;
  s[threadIdx.x] = v;
  __syncthreads();
  for (int off = 1; off < SCAN_B; off <<= 1) {
    int t = (threadIdx.x >= off) ? s[threadIdx.x - off] : 0;
    __syncthreads();
    s[threadIdx.x] += t;
    __syncthreads();
  }
  if (i < n) a[i] = s[threadIdx.x];
  if (threadIdx.x == SCAN_B - 1) bsum[blockIdx.x] = s[SCAN_B - 1];
}

__global__ __launch_bounds__(256) void scan_mid(int* __restrict__ bsum, int nb) {
  __shared__ int s[256];
  int v = (threadIdx.x < nb) ? bsum[threadIdx.x] : 0;
  s[threadIdx.x] = v;
  __syncthreads();
  for (int off = 1; off < 256; off <<= 1) {
    int t = (threadIdx.x >= off) ? s[threadIdx.x - off] : 0;
    __syncthreads();
    s[threadIdx.x] += t;
    __syncthreads();
  }
  if (threadIdx.x < nb) bsum[threadIdx.x] = s[threadIdx.x];
}

__global__ __launch_bounds__(SCAN_B) void scan_add(int* __restrict__ a,
                                                   const int* __restrict__ bsum, int n) {
  int i = blockIdx.x * SCAN_B + threadIdx.x;
  if (i >= n || blockIdx.x == 0) return;
  a[i] += bsum[blockIdx.x - 1];
}

// ---------------------------------------------------------------------------
// Pass 1b: scatter packed edges into bucket-grouped ebuk via LDS cursors.
// packed = (dst & 511) << 17 | src.
// ---------------------------------------------------------------------------
__global__ __launch_bounds__(256) void bucket_scatter_kernel(
    const int* __restrict__ src, const int* __restrict__ dst,
    const int* __restrict__ scanned, int* __restrict__ ebuk) {
  __shared__ int cur[NBUK];
  int tid = threadIdx.x;
  int idx = tid * NB1 + blockIdx.x;
  cur[tid] = (idx == 0) ? 0 : scanned[idx - 1];
  __syncthreads();
  int e0 = blockIdx.x * EPB1;
  int e1 = e0 + EPB1; if (e1 > NE) e1 = NE;
  for (int e = e0 + tid; e < e1; e += 256) {
    int d = dst[e];
    int pos = atomicAdd(&cur[d >> BSHIFT], 1);
    ebuk[pos] = ((d & (BNODES - 1)) << SRC_BITS) | src[e];
  }
}

// ---------------------------------------------------------------------------
// Pass 2: one block per coarse bucket. LDS histogram -> LDS scan ->
// row_start write -> LDS-cursor scatter of col.
// ---------------------------------------------------------------------------
__global__ __launch_bounds__(512) void bucket_csr_kernel(
    const int* __restrict__ ebuk, const int* __restrict__ scanned,
    int* __restrict__ row_start, int* __restrict__ col) {
  __shared__ int h[BNODES];
  __shared__ int cur[BNODES];
  int b = blockIdx.x;
  int tid = threadIdx.x;
  int base = (b == 0) ? 0 : scanned[b * NB1 - 1];
  int end  = scanned[(b + 1) * NB1 - 1];
  h[tid] = 0;
  __syncthreads();
  for (int p = base + tid; p < end; p += 512)
    atomicAdd(&h[ebuk[p] >> SRC_BITS], 1);
  __syncthreads();
  int orig = h[tid];
  for (int off = 1; off < 512; off <<= 1) {
    int t = (tid >= off) ? h[tid - off] : 0;
    __syncthreads();
    h[tid] += t;
    __syncthreads();
  }
  int excl = h[tid] - orig;
  int n = (b << BSHIFT) + tid;
  if (n < N_NODES) row_start[n] = base + excl;
  if (b == NBUK_USED - 1 && tid == 0) row_start[N_NODES] = end;
  cur[tid] = base + excl;
  __syncthreads();
  for (int p = base + tid; p < end; p += 512) {
    int packed = ebuk[p];
    int pos = atomicAdd(&cur[packed >> SRC_BITS], 1);
    col[pos] = packed & SRC_MASK;
  }
}

// ---------------------------------------------------------------------------
// Fused layer 1: per block (4 waves, 64 nodes), each wave
//   (1) aggregates its own 16 nodes into wave-private LDS rows (bf16 mean),
//   (2) runs the [mean|x] @ [Wl;Wr]^T MFMA GEMM reading A from those rows,
//   (3) BN+ReLU, restages bf16 in the same rows, coalesced uint4 store.
// Zero __syncthreads: all LDS rows are wave-private; wave lockstep orders
// the LDS read->write->read chain.
// ---------------------------------------------------------------------------
__global__ __launch_bounds__(256) void fused_layer1(
    const unsigned short* __restrict__ xh, const int* __restrict__ row_start,
    const int* __restrict__ col,
    const float* __restrict__ Wl, const float* __restrict__ bl,
    const float* __restrict__ Wr,
    const float* __restrict__ g, const float* __restrict__ beta,
    const float* __restrict__ m, const float* __restrict__ v,
    unsigned short* __restrict__ h1h) {
  __shared__ unsigned short hts[64][72];   // rows padded to 144B
  int tid = threadIdx.x;
  int w = tid >> 6, lane = tid & 63;
  int oct = lane >> 3, sl = lane & 7;
  int q = lane & 15, kg = lane >> 4;
  int base_w = blockIdx.x * 64 + w * 16;

  // ---- phase 1: gather-aggregate 16 nodes into own LDS rows ----
  for (int i = 0; i < 16; ++i) {
    int node = base_w + i;
    if (node > N_NODES - 1) node = N_NODES - 1;
    int r0 = row_start[node];
    int r1 = row_start[node + 1];
    float a0 = 0.f, a1 = 0.f, a2 = 0.f, a3 = 0.f;
    float a4 = 0.f, a5 = 0.f, a6 = 0.f, a7 = 0.f;
    float c0 = 0.f, c1 = 0.f, c2 = 0.f, c3 = 0.f;
    float c4 = 0.f, c5 = 0.f, c6 = 0.f, c7 = 0.f;
    int j = r0 + oct;
    for (; j + 8 < r1; j += 16) {
      int s0 = col[j];
      int s1 = col[j + 8];
      uint4 u0 = *reinterpret_cast<const uint4*>(xh + s0 * D + 8 * sl);
      uint4 u1 = *reinterpret_cast<const uint4*>(xh + s1 * D + 8 * sl);
      a0 += bflo(u0.x); a1 += bfhi(u0.x); a2 += bflo(u0.y); a3 += bfhi(u0.y);
      a4 += bflo(u0.z); a5 += bfhi(u0.z); a6 += bflo(u0.w); a7 += bfhi(u0.w);
      c0 += bflo(u1.x); c1 += bfhi(u1.x); c2 += bflo(u1.y); c3 += bfhi(u1.y);
      c4 += bflo(u1.z); c5 += bfhi(u1.z); c6 += bflo(u1.w); c7 += bfhi(u1.w);
    }
    if (j < r1) {
      int s0 = col[j];
      uint4 u0 = *reinterpret_cast<const uint4*>(xh + s0 * D + 8 * sl);
      a0 += bflo(u0.x); a1 += bfhi(u0.x); a2 += bflo(u0.y); a3 += bfhi(u0.y);
      a4 += bflo(u0.z); a5 += bfhi(u0.z); a6 += bflo(u0.w); a7 += bfhi(u0.w);
    }
    a0 += c0; a1 += c1; a2 += c2; a3 += c3;
    a4 += c4; a5 += c5; a6 += c6; a7 += c7;
#pragma unroll
    for (int d = 8; d <= 32; d <<= 1) {
      a0 += __shfl_xor(a0, d); a1 += __shfl_xor(a1, d);
      a2 += __shfl_xor(a2, d); a3 += __shfl_xor(a3, d);
      a4 += __shfl_xor(a4, d); a5 += __shfl_xor(a5, d);
      a6 += __shfl_xor(a6, d); a7 += __shfl_xor(a7, d);
    }
    if (oct == 0) {
      float inv = 1.f / fmaxf((float)(r1 - r0), 1.f);
      uint4 o;
      o.x = pack2(a0 * inv, a1 * inv);
      o.y = pack2(a2 * inv, a3 * inv);
      o.z = pack2(a4 * inv, a5 * inv);
      o.w = pack2(a6 * inv, a7 * inv);
      *reinterpret_cast<uint4*>(&hts[w * 16 + i][8 * sl]) = o;
    }
  }

  // ---- weights + BN constants (loaded after gather to cap VGPR pressure) ----
  bf16x8 b[4][4];
  float sc[4], sh[4];
#pragma unroll
  for (int f = 0; f < 4; ++f) {
    int c = f * 16 + q;
    b[0][f] = ldw(Wl + c * D + kg * 8);
    b[1][f] = ldw(Wl + c * D + 32 + kg * 8);
    b[2][f] = ldw(Wr + c * D + kg * 8);
    b[3][f] = ldw(Wr + c * D + 32 + kg * 8);
    float s = g[c] * rsqrtf(v[c] + BN_EPS);
    sc[f] = s;
    sh[f] = (bl[c] - m[c]) * s + beta[c];
  }

  // ---- phase 2: MFMA GEMM (A rows are wave-private LDS + global xh) ----
  const unsigned short* mrow = &hts[w * 16 + q][0];
  bf16x8 a0 = *reinterpret_cast<const bf16x8*>(mrow + kg * 8);
  bf16x8 a1 = *reinterpret_cast<const bf16x8*>(mrow + 32 + kg * 8);
  int nodeA = base_w + q;
  if (nodeA > N_NODES - 1) nodeA = N_NODES - 1;
  const unsigned short* xrow = xh + (size_t)nodeA * D;
  bf16x8 a2 = *reinterpret_cast<const bf16x8*>(xrow + kg * 8);
  bf16x8 a3 = *reinterpret_cast<const bf16x8*>(xrow + 32 + kg * 8);

  f32x4 acc[4];
#pragma unroll
  for (int f = 0; f < 4; ++f) {
    acc[f] = (f32x4){0.f, 0.f, 0.f, 0.f};
    acc[f] = __builtin_amdgcn_mfma_f32_16x16x32_bf16(a0, b[0][f], acc[f], 0, 0, 0);
    acc[f] = __builtin_amdgcn_mfma_f32_16x16x32_bf16(a1, b[1][f], acc[f], 0, 0, 0);
    acc[f] = __builtin_amdgcn_mfma_f32_16x16x32_bf16(a2, b[2][f], acc[f], 0, 0, 0);
    acc[f] = __builtin_amdgcn_mfma_f32_16x16x32_bf16(a3, b[3][f], acc[f], 0, 0, 0);
  }

  // ---- phase 3: BN+ReLU -> bf16 back into own rows ----
#pragma unroll
  for (int r = 0; r < 4; ++r)
#pragma unroll
    for (int f = 0; f < 4; ++f)
      hts[w * 16 + kg * 4 + r][f * 16 + q] =
          f2bf(fmaxf(acc[f][r] * sc[f] + sh[f], 0.f));

  // ---- phase 4: coalesced store ----
  int node_s = base_w + q;
  const uint4* hr4 = reinterpret_cast<const uint4*>(&hts[w * 16 + q][0]);
  uint4 s0 = hr4[kg];
  uint4 s1 = hr4[kg + 4];
  if (node_s < N_NODES) {
    uint4* gout = reinterpret_cast<uint4*>(h1h + (size_t)node_s * D);
    gout[kg] = s0;
    gout[kg + 4] = s1;
  }
}

// ---------------------------------------------------------------------------
// Fused layer 2: aggregate(h1h) -> MFMA GEMM -> BN+ReLU -> MFMA MLP head ->
// sigmoid -> out. Same wave-private zero-barrier structure.
// ---------------------------------------------------------------------------
__global__ __launch_bounds__(256) void fused_layer2(
    const unsigned short* __restrict__ h1h, const int* __restrict__ row_start,
    const int* __restrict__ col,
    const float* __restrict__ Wl, const float* __restrict__ bl,
    const float* __restrict__ Wr,
    const float* __restrict__ g, const float* __restrict__ beta,
    const float* __restrict__ m, const float* __restrict__ v,
    const float* __restrict__ mW1, const float* __restrict__ mb1,
    const float* __restrict__ mW2, const float* __restrict__ mb2,
    float* __restrict__ out) {
  __shared__ unsigned short hts[64][72];
  int tid = threadIdx.x;
  int w = tid >> 6, lane = tid & 63;
  int oct = lane >> 3, sl = lane & 7;
  int q = lane & 15, kg = lane >> 4;
  int base_w = blockIdx.x * 64 + w * 16;

  // ---- phase 1: gather-aggregate h1 means into own LDS rows ----
  for (int i = 0; i < 16; ++i) {
    int node = base_w + i;
    if (node > N_NODES - 1) node = N_NODES - 1;
    int r0 = row_start[node];
    int r1 = row_start[node + 1];
    float a0 = 0.f, a1 = 0.f, a2 = 0.f, a3 = 0.f;
    float a4 = 0.f, a5 = 0.f, a6 = 0.f, a7 = 0.f;
    float c0 = 0.f, c1 = 0.f, c2 = 0.f, c3 = 0.f;
    float c4 = 0.f, c5 = 0.f, c6 = 0.f, c7 = 0.f;
    int j = r0 + oct;
    for (; j + 8 < r1; j += 16) {
      int s0 = col[j];
      int s1 = col[j + 8];
      uint4 u0 = *reinterpret_cast<const uint4*>(h1h + s0 * D + 8 * sl);
      uint4 u1 = *reinterpret_cast<const uint4*>(h1h + s1 * D + 8 * sl);
      a0 += bflo(u0.x); a1 += bfhi(u0.x); a2 += bflo(u0.y); a3 += bfhi(u0.y);
      a4 += bflo(u0.z); a5 += bfhi(u0.z); a6 += bflo(u0.w); a7 += bfhi(u0.w);
      c0 += bflo(u1.x); c1 += bfhi(u1.x); c2 += bflo(u1.y); c3 += bfhi(u1.y);
      c4 += bflo(u1.z); c5 += bfhi(u1.z); c6 += bflo(u1.w); c7 += bfhi(u1.w);
    }
    if (j < r1) {
      int s0 = col[j];
      uint4 u0 = *reinterpret_cast<const uint4*>(h1h + s0 * D + 8 * sl);
      a0 += bflo(u0.x); a1 += bfhi(u0.x); a2 += bflo(u0.y); a3 += bfhi(u0.y);
      a4 += bflo(u0.z); a5 += bfhi(u0.z); a6 += bflo(u0.w); a7 += bfhi(u0.w);
    }
    a0 += c0; a1 += c1; a2 += c2; a3 += c3;
    a4 += c4; a5 += c5; a6 += c6; a7 += c7;
#pragma unroll
    for (int d = 8; d <= 32; d <<= 1) {
      a0 += __shfl_xor(a0, d); a1 += __shfl_xor(a1, d);
      a2 += __shfl_xor(a2, d); a3 += __shfl_xor(a3, d);
      a4 += __shfl_xor(a4, d); a5 += __shfl_xor(a5, d);
      a6 += __shfl_xor(a6, d); a7 += __shfl_xor(a7, d);
    }
    if (oct == 0) {
      float inv = 1.f / fmaxf((float)(r1 - r0), 1.f);
      uint4 o;
      o.x = pack2(a0 * inv, a1 * inv);
      o.y = pack2(a2 * inv, a3 * inv);
      o.z = pack2(a4 * inv, a5 * inv);
      o.w = pack2(a6 * inv, a7 * inv);
      *reinterpret_cast<uint4*>(&hts[w * 16 + i][8 * sl]) = o;
    }
  }

  // ---- weights + BN constants + head constants ----
  bf16x8 b[4][4];
  float sc[4], sh[4];
#pragma unroll
  for (int f = 0; f < 4; ++f) {
    int c = f * 16 + q;
    b[0][f] = ldw(Wl + c * D + kg * 8);
    b[1][f] = ldw(Wl + c * D + 32 + kg * 8);
    b[2][f] = ldw(Wr + c * D + kg * 8);
    b[3][f] = ldw(Wr + c * D + 32 + kg * 8);
    float s = g[c] * rsqrtf(v[c] + BN_EPS);
    sc[f] = s;
    sh[f] = (bl[c] - m[c]) * s + beta[c];
  }
  bf16x8 bh[2][2];
#pragma unroll
  for (int f = 0; f < 2; ++f)
#pragma unroll
    for (int s = 0; s < 2; ++s)
      bh[s][f] = ldw(mW1 + (f * 16 + q) * D + s * 32 + kg * 8);
  float mw2v0 = mW2[q], mw2v1 = mW2[16 + q];
  float mb1v0 = mb1[q], mb1v1 = mb1[16 + q];
  float mb2v = mb2[0];

  // ---- phase 2: MFMA GEMM ----
  const unsigned short* mrow = &hts[w * 16 + q][0];
  bf16x8 a0 = *reinterpret_cast<const bf16x8*>(mrow + kg * 8);
  bf16x8 a1 = *reinterpret_cast<const bf16x8*>(mrow + 32 + kg * 8);
  int nodeA = base_w + q;
  if (nodeA > N_NODES - 1) nodeA = N_NODES - 1;
  const unsigned short* xrow = h1h + (size_t)nodeA * D;
  bf16x8 a2 = *reinterpret_cast<const bf16x8*>(xrow + kg * 8);
  bf16x8 a3 = *reinterpret_cast<const bf16x8*>(xrow + 32 + kg * 8);

  f32x4 acc[4];
#pragma unroll
  for (int f = 0; f < 4; ++f) {
    acc[f] = (f32x4){0.f, 0.f, 0.f, 0.f};
    acc[f] = __builtin_amdgcn_mfma_f32_16x16x32_bf16(a0, b[0][f], acc[f], 0, 0, 0);
    acc[f] = __builtin_amdgcn_mfma_f32_16x16x32_bf16(a1, b[1][f], acc[f], 0, 0, 0);
    acc[f] = __builtin_amdgcn_mfma_f32_16x16x32_bf16(a2, b[2][f], acc[f], 0, 0, 0);
    acc[f] = __builtin_amdgcn_mfma_f32_16x16x32_bf16(a3, b[3][f], acc[f], 0, 0, 0);
  }

  // ---- phase 3: BN+ReLU -> bf16 h2 into own rows (mean no longer needed) ----
#pragma unroll
  for (int r = 0; r < 4; ++r)
#pragma unroll
    for (int f = 0; f < 4; ++f)
      hts[w * 16 + kg * 4 + r][f * 16 + q] =
          f2bf(fmaxf(acc[f][r] * sc[f] + sh[f], 0.f));

  // ---- phase 4: MFMA MLP head (M=16 nodes, N=32, K=64) ----
  const unsigned short* hrow = &hts[w * 16 + q][0];
  bf16x8 ha0 = *reinterpret_cast<const bf16x8*>(hrow + kg * 8);
  bf16x8 ha1 = *reinterpret_cast<const bf16x8*>(hrow + 32 + kg * 8);
  f32x4 az0 = (f32x4){0.f, 0.f, 0.f, 0.f};
  f32x4 az1 = (f32x4){0.f, 0.f, 0.f, 0.f};
  az0 = __builtin_amdgcn_mfma_f32_16x16x32_bf16(ha0, bh[0][0], az0, 0, 0, 0);
  az0 = __builtin_amdgcn_mfma_f32_16x16x32_bf16(ha1, bh[1][0], az0, 0, 0, 0);
  az1 = __builtin_amdgcn_mfma_f32_16x16x32_bf16(ha0, bh[0][1], az1, 0, 0, 0);
  az1 = __builtin_amdgcn_mfma_f32_16x16x32_bf16(ha1, bh[1][1], az1, 0, 0, 0);

  float ps[4];
#pragma unroll
  for (int r = 0; r < 4; ++r)
    ps[r] = fmaxf(az0[r] + mb1v0, 0.f) * mw2v0 +
            fmaxf(az1[r] + mb1v1, 0.f) * mw2v1;
#pragma unroll
  for (int d = 1; d <= 8; d <<= 1) {
    ps[0] += __shfl_xor(ps[0], d);
    ps[1] += __shfl_xor(ps[1], d);
    ps[2] += __shfl_xor(ps[2], d);
    ps[3] += __shfl_xor(ps[3], d);
  }
  if (q == 0) {
#pragma unroll
    for (int r = 0; r < 4; ++r) {
      int node = base_w + kg * 4 + r;
      if (node < N_NODES)
        out[node] = 1.0f / (1.0f + expf(-(ps[r] + mb2v)));
    }
  }
}

// ---------------------------------------------------------------------------
extern "C" void kernel_launch(void* const* d_in, const int* in_sizes, int n_in,
                              void* d_out, int out_size, void* d_ws, size_t ws_size,
                              hipStream_t stream) {
  const float* x    = (const float*)d_in[0];
  const int*   ei   = (const int*)d_in[1];
  const float* Wl1  = (const float*)d_in[2];
  const float* bl1  = (const float*)d_in[3];
  const float* Wr1  = (const float*)d_in[4];
  const float* g1   = (const float*)d_in[5];
  const float* be1  = (const float*)d_in[6];
  const float* m1   = (const float*)d_in[7];
  const float* v1   = (const float*)d_in[8];
  const float* Wl2  = (const float*)d_in[9];
  const float* bl2  = (const float*)d_in[10];
  const float* Wr2  = (const float*)d_in[11];
  const float* g2   = (const float*)d_in[12];
  const float* be2  = (const float*)d_in[13];
  const float* m2   = (const float*)d_in[14];
  const float* v2   = (const float*)d_in[15];
  const float* mW1  = (const float*)d_in[16];
  const float* mb1  = (const float*)d_in[17];
  const float* mW2  = (const float*)d_in[18];
  const float* mb2  = (const float*)d_in[19];
  float* out = (float*)d_out;

  const int* src = ei;
  const int* dst = ei + NE;

  // ws layout (no memsets; everything written before read):
  //   xh | h1h (bf16 N*D each) | ebuk (NE int, packed) | col (NE int)
  //   | row_start (N+16) | bhist (NSCAN) | bsum (512)
  unsigned short* xh  = (unsigned short*)d_ws;
  unsigned short* h1h = xh + (size_t)N_NODES * D;
  int* ebuk      = (int*)(h1h + (size_t)N_NODES * D);
  int* col       = ebuk + NE;
  int* row_start = col + NE;
  int* bhist     = row_start + (N_NODES + 16);
  int* bsum      = bhist + NSCAN;

  const int scan_blocks = NSCAN / SCAN_B;                    // 128
  const int fused_blocks = (N_NODES + 63) / 64;              // 1563

  // --- CSR build (LDS bucket counting sort, zero global atomics) ---
  bucket_hist_kernel<<<NB1, 256, 0, stream>>>(dst, bhist, x, xh);
  scan_part<<<scan_blocks, SCAN_B, 0, stream>>>(bhist, bsum, NSCAN);
  scan_mid<<<1, 256, 0, stream>>>(bsum, scan_blocks);
  scan_add<<<scan_blocks, SCAN_B, 0, stream>>>(bhist, bsum, NSCAN);
  bucket_scatter_kernel<<<NB1, 256, 0, stream>>>(src, dst, bhist, ebuk);
  bucket_csr_kernel<<<NBUK_USED, 512, 0, stream>>>(ebuk, bhist, row_start, col);

  // --- fused layers ---
  fused_layer1<<<fused_blocks, 256, 0, stream>>>(xh, row_start, col,
                                                 Wl1, bl1, Wr1,
                                                 g1, be1, m1, v1, h1h);
  fused_layer2<<<fused_blocks, 256, 0, stream>>>(h1h, row_start, col,
                                                 Wl2, bl2, Wr2,
                                                 g2, be2, m2, v2,
                                                 mW1, mb1, mW2, mb2, out);
}

// Round 12
// 269.334 us; speedup vs baseline: 1.3511x; 1.3511x over previous
//
#include <hip/hip_runtime.h>
#include <math.h>

#define N_NODES 100000
#define NE      1200000
#define D       64
#define H2      32
#define BN_EPS  1e-5f
#define SCAN_B  512

// bucket sort parameters
#define BSHIFT  9
#define BNODES  512                      // nodes per coarse bucket
#define NBUK    256                      // bucket slots (used: 196)
#define NBUK_USED ((N_NODES + BNODES - 1) / BNODES)   // 196
#define NB1     512                      // pass-1 blocks
#define EPB1    ((NE + NB1 - 1) / NB1)   // 2344 edges per pass-1 block
#define NSCAN   (NBUK * NB1)             // 131072 scan entries
#define SRC_BITS 17
#define SRC_MASK ((1 << SRC_BITS) - 1)

typedef short bf16x8 __attribute__((ext_vector_type(8)));
typedef float f32x4 __attribute__((ext_vector_type(4)));

// ---- bf16 helpers (RNE) ----------------------------------------------------
__device__ __forceinline__ unsigned short f2bf(float f) {
  unsigned int u = __float_as_uint(f);
  u += 0x7fffu + ((u >> 16) & 1u);
  return (unsigned short)(u >> 16);
}
__device__ __forceinline__ float bflo(unsigned int u) { return __uint_as_float(u << 16); }
__device__ __forceinline__ float bfhi(unsigned int u) { return __uint_as_float(u & 0xffff0000u); }
__device__ __forceinline__ unsigned int pack2(float lo, float hi) {
  return (unsigned int)f2bf(lo) | ((unsigned int)f2bf(hi) << 16);
}

__device__ __forceinline__ bf16x8 ldw(const float* p) {
  float4 w0 = *reinterpret_cast<const float4*>(p);
  float4 w1 = *reinterpret_cast<const float4*>(p + 4);
  bf16x8 b;
  b[0] = (short)f2bf(w0.x); b[1] = (short)f2bf(w0.y);
  b[2] = (short)f2bf(w0.z); b[3] = (short)f2bf(w0.w);
  b[4] = (short)f2bf(w1.x); b[5] = (short)f2bf(w1.y);
  b[6] = (short)f2bf(w1.z); b[7] = (short)f2bf(w1.w);
  return b;
}

// ---------------------------------------------------------------------------
// Pass 1a: per-block LDS histogram of coarse buckets (dst>>9); also converts
// x (f32) -> xh (bf16). All atomics are LDS.
// ---------------------------------------------------------------------------
__global__ __launch_bounds__(256) void bucket_hist_kernel(
    const int* __restrict__ dst, int* __restrict__ bhist,
    const float* __restrict__ x, unsigned short* __restrict__ xh) {
  __shared__ int h[NBUK];
  int tid = threadIdx.x;
  h[tid] = 0;
  __syncthreads();
  int e0 = blockIdx.x * EPB1;
  int e1 = e0 + EPB1; if (e1 > NE) e1 = NE;
  for (int e = e0 + tid; e < e1; e += 256)
    atomicAdd(&h[dst[e] >> BSHIFT], 1);
  __syncthreads();
  bhist[tid * NB1 + blockIdx.x] = h[tid];

  const int nquads = N_NODES * D / 4;
  for (int i = blockIdx.x * 256 + tid; i < nquads; i += NB1 * 256) {
    float4 v = reinterpret_cast<const float4*>(x)[i];
    ushort4 o;
    o.x = f2bf(v.x); o.y = f2bf(v.y); o.z = f2bf(v.z); o.w = f2bf(v.w);
    reinterpret_cast<ushort4*>(xh)[i] = o;
  }
}

// ---------------------------------------------------------------------------
// Blocked inclusive scan over bhist[0..NSCAN).
// ---------------------------------------------------------------------------
__global__ __launch_bounds__(SCAN_B) void scan_part(int* __restrict__ a,
                                                    int* __restrict__ bsum, int n) {
  __shared__ int s[SCAN_B];
  int i = blockIdx.x * SCAN_B + threadIdx.x;
  int v = (i < n) ? a[i] : 0;
  s[threadIdx.x] = v;
  __syncthreads();
  for (int off = 1; off < SCAN_B; off <<= 1) {
    int t = (threadIdx.x >= off) ? s[threadIdx.x - off] : 0;
    __syncthreads();
    s[threadIdx.x] += t;
    __syncthreads();
  }
  if (i < n) a[i] = s[threadIdx.x];
  if (threadIdx.x == SCAN_B - 1) bsum[blockIdx.x] = s[SCAN_B - 1];
}

__global__ __launch_bounds__(256) void scan_mid(int* __restrict__ bsum, int nb) {
  __shared__ int s[256];
  int v = (threadIdx.x < nb) ? bsum[threadIdx.x] : 0;
  s[threadIdx.x] = v;
  __syncthreads();
  for (int off = 1; off < 256; off <<= 1) {
    int t = (threadIdx.x >= off) ? s[threadIdx.x - off] : 0;
    __syncthreads();
    s[threadIdx.x] += t;
    __syncthreads();
  }
  if (threadIdx.x < nb) bsum[threadIdx.x] = s[threadIdx.x];
}

__global__ __launch_bounds__(SCAN_B) void scan_add(int* __restrict__ a,
                                                   const int* __restrict__ bsum, int n) {
  int i = blockIdx.x * SCAN_B + threadIdx.x;
  if (i >= n || blockIdx.x == 0) return;
  a[i] += bsum[blockIdx.x - 1];
}

// ---------------------------------------------------------------------------
// Pass 1b: scatter packed edges into bucket-grouped ebuk via LDS cursors.
// packed = (dst & 511) << 17 | src.
// ---------------------------------------------------------------------------
__global__ __launch_bounds__(256) void bucket_scatter_kernel(
    const int* __restrict__ src, const int* __restrict__ dst,
    const int* __restrict__ scanned, int* __restrict__ ebuk) {
  __shared__ int cur[NBUK];
  int tid = threadIdx.x;
  int idx = tid * NB1 + blockIdx.x;
  cur[tid] = (idx == 0) ? 0 : scanned[idx - 1];
  __syncthreads();
  int e0 = blockIdx.x * EPB1;
  int e1 = e0 + EPB1; if (e1 > NE) e1 = NE;
  for (int e = e0 + tid; e < e1; e += 256) {
    int d = dst[e];
    int pos = atomicAdd(&cur[d >> BSHIFT], 1);
    ebuk[pos] = ((d & (BNODES - 1)) << SRC_BITS) | src[e];
  }
}

// ---------------------------------------------------------------------------
// Pass 2: one block per coarse bucket. LDS histogram -> LDS scan ->
// row_start write -> LDS-cursor scatter of col.
// ---------------------------------------------------------------------------
__global__ __launch_bounds__(512) void bucket_csr_kernel(
    const int* __restrict__ ebuk, const int* __restrict__ scanned,
    int* __restrict__ row_start, int* __restrict__ col) {
  __shared__ int h[BNODES];
  __shared__ int cur[BNODES];
  int b = blockIdx.x;
  int tid = threadIdx.x;
  int base = (b == 0) ? 0 : scanned[b * NB1 - 1];
  int end  = scanned[(b + 1) * NB1 - 1];
  h[tid] = 0;
  __syncthreads();
  for (int p = base + tid; p < end; p += 512)
    atomicAdd(&h[ebuk[p] >> SRC_BITS], 1);
  __syncthreads();
  int orig = h[tid];
  for (int off = 1; off < 512; off <<= 1) {
    int t = (tid >= off) ? h[tid - off] : 0;
    __syncthreads();
    h[tid] += t;
    __syncthreads();
  }
  int excl = h[tid] - orig;
  int n = (b << BSHIFT) + tid;
  if (n < N_NODES) row_start[n] = base + excl;
  if (b == NBUK_USED - 1 && tid == 0) row_start[N_NODES] = end;
  cur[tid] = base + excl;
  __syncthreads();
  for (int p = base + tid; p < end; p += 512) {
    int packed = ebuk[p];
    int pos = atomicAdd(&cur[packed >> SRC_BITS], 1);
    col[pos] = packed & SRC_MASK;
  }
}

// ---------------------------------------------------------------------------
// Gather-aggregate v4 (bf16 rows, 128B each). Wave = 4 nodes as 2 pairs;
// the two nodes of a pair are aggregated CONCURRENTLY (independent
// accumulator sets, interleaved loads) so each lane keeps 2 gathers in
// flight even at mean degree ~12 where the old intra-node unroll never
// engaged. 8 lanes per edge-row (uint4 = 8 bf16/lane).
// ---------------------------------------------------------------------------
__global__ __launch_bounds__(256) void aggregate_kernel(
    const unsigned short* __restrict__ feat, const int* __restrict__ row_start,
    const int* __restrict__ col, unsigned short* __restrict__ meanout) {
  int w = threadIdx.x >> 6;
  int lane = threadIdx.x & 63;
  int oct = lane >> 3;
  int sl = lane & 7;
  int nbase = blockIdx.x * 16 + w * 4;
  if (nbase >= N_NODES) return;
#pragma unroll
  for (int i = 0; i < 4; i += 2) {
    int nodeA = nbase + i;
    if (nodeA >= N_NODES) return;
    int nodeB = nodeA + 1;
    bool hasB = nodeB < N_NODES;
    int r0a = row_start[nodeA];
    int r1a = row_start[nodeA + 1];
    int r0b = 0, r1b = 0;
    if (hasB) { r0b = row_start[nodeB]; r1b = row_start[nodeB + 1]; }

    float a0 = 0.f, a1 = 0.f, a2 = 0.f, a3 = 0.f;
    float a4 = 0.f, a5 = 0.f, a6 = 0.f, a7 = 0.f;
    float b0 = 0.f, b1 = 0.f, b2 = 0.f, b3 = 0.f;
    float b4 = 0.f, b5 = 0.f, b6 = 0.f, b7 = 0.f;

    int ja = r0a + oct;
    int jb = r0b + oct;
    while (ja < r1a || jb < r1b) {
      if (ja < r1a) {
        int s = col[ja];
        uint4 u = *reinterpret_cast<const uint4*>(feat + s * D + 8 * sl);
        a0 += bflo(u.x); a1 += bfhi(u.x); a2 += bflo(u.y); a3 += bfhi(u.y);
        a4 += bflo(u.z); a5 += bfhi(u.z); a6 += bflo(u.w); a7 += bfhi(u.w);
        ja += 8;
      }
      if (jb < r1b) {
        int s = col[jb];
        uint4 u = *reinterpret_cast<const uint4*>(feat + s * D + 8 * sl);
        b0 += bflo(u.x); b1 += bfhi(u.x); b2 += bflo(u.y); b3 += bfhi(u.y);
        b4 += bflo(u.z); b5 += bfhi(u.z); b6 += bflo(u.w); b7 += bfhi(u.w);
        jb += 8;
      }
    }

#pragma unroll
    for (int d = 8; d <= 32; d <<= 1) {
      a0 += __shfl_xor(a0, d); a1 += __shfl_xor(a1, d);
      a2 += __shfl_xor(a2, d); a3 += __shfl_xor(a3, d);
      a4 += __shfl_xor(a4, d); a5 += __shfl_xor(a5, d);
      a6 += __shfl_xor(a6, d); a7 += __shfl_xor(a7, d);
      b0 += __shfl_xor(b0, d); b1 += __shfl_xor(b1, d);
      b2 += __shfl_xor(b2, d); b3 += __shfl_xor(b3, d);
      b4 += __shfl_xor(b4, d); b5 += __shfl_xor(b5, d);
      b6 += __shfl_xor(b6, d); b7 += __shfl_xor(b7, d);
    }
    if (oct == 0) {
      float inv = 1.f / fmaxf((float)(r1a - r0a), 1.f);
      uint4 o;
      o.x = pack2(a0 * inv, a1 * inv);
      o.y = pack2(a2 * inv, a3 * inv);
      o.z = pack2(a4 * inv, a5 * inv);
      o.w = pack2(a6 * inv, a7 * inv);
      *reinterpret_cast<uint4*>(meanout + nodeA * D + 8 * sl) = o;
    } else if (oct == 1 && hasB) {
      float inv = 1.f / fmaxf((float)(r1b - r0b), 1.f);
      uint4 o;
      o.x = pack2(b0 * inv, b1 * inv);
      o.y = pack2(b2 * inv, b3 * inv);
      o.z = pack2(b4 * inv, b5 * inv);
      o.w = pack2(b6 * inv, b7 * inv);
      *reinterpret_cast<uint4*>(meanout + nodeB * D + 8 * sl) = o;
    }
  }
}

// ---------------------------------------------------------------------------
// Layer 1 via MFMA. Output staged as bf16 in a padded LDS tile (144B rows:
// 2-way bank aliasing only), then stored with coalesced uint4 writes.
// ---------------------------------------------------------------------------
#define MT 2
__global__ __launch_bounds__(256) void layer1_mfma(
    const unsigned short* __restrict__ meanh, const unsigned short* __restrict__ xh,
    const float* __restrict__ Wl, const float* __restrict__ bl,
    const float* __restrict__ Wr,
    const float* __restrict__ g, const float* __restrict__ beta,
    const float* __restrict__ m, const float* __restrict__ v,
    unsigned short* __restrict__ h1h) {
  __shared__ float scale_s[D];
  __shared__ float shift_s[D];
  __shared__ unsigned short hts[64][72];   // bf16 out tile, rows padded to 144B
  int tid = threadIdx.x;
  if (tid < D) {
    float s = g[tid] * rsqrtf(v[tid] + BN_EPS);
    scale_s[tid] = s;
    shift_s[tid] = (bl[tid] - m[tid]) * s + beta[tid];
  }
  __syncthreads();

  int w = tid >> 6, lane = tid & 63, q = lane & 15, kg = lane >> 4;

  bf16x8 b[4][4];
#pragma unroll
  for (int f = 0; f < 4; ++f) {
    int c = f * 16 + q;
    b[0][f] = ldw(Wl + c * D + kg * 8);
    b[1][f] = ldw(Wl + c * D + 32 + kg * 8);
    b[2][f] = ldw(Wr + c * D + kg * 8);
    b[3][f] = ldw(Wr + c * D + 32 + kg * 8);
  }

#pragma unroll
  for (int mt = 0; mt < MT; ++mt) {
    int base = blockIdx.x * (64 * MT) + mt * 64 + w * 16;
    int nodeA = base + q;
    if (nodeA > N_NODES - 1) nodeA = N_NODES - 1;
    const unsigned short* mrow = meanh + (size_t)nodeA * D;
    const unsigned short* xrow = xh + (size_t)nodeA * D;
    bf16x8 a0 = *reinterpret_cast<const bf16x8*>(mrow + kg * 8);
    bf16x8 a1 = *reinterpret_cast<const bf16x8*>(mrow + 32 + kg * 8);
    bf16x8 a2 = *reinterpret_cast<const bf16x8*>(xrow + kg * 8);
    bf16x8 a3 = *reinterpret_cast<const bf16x8*>(xrow + 32 + kg * 8);

    f32x4 acc[4];
#pragma unroll
    for (int f = 0; f < 4; ++f) {
      acc[f] = (f32x4){0.f, 0.f, 0.f, 0.f};
      acc[f] = __builtin_amdgcn_mfma_f32_16x16x32_bf16(a0, b[0][f], acc[f], 0, 0, 0);
      acc[f] = __builtin_amdgcn_mfma_f32_16x16x32_bf16(a1, b[1][f], acc[f], 0, 0, 0);
      acc[f] = __builtin_amdgcn_mfma_f32_16x16x32_bf16(a2, b[2][f], acc[f], 0, 0, 0);
      acc[f] = __builtin_amdgcn_mfma_f32_16x16x32_bf16(a3, b[3][f], acc[f], 0, 0, 0);
    }

    // BN + ReLU -> bf16 LDS tile (own-wave rows only)
#pragma unroll
    for (int r = 0; r < 4; ++r)
#pragma unroll
      for (int f = 0; f < 4; ++f) {
        int c = f * 16 + q;
        hts[w * 16 + kg * 4 + r][c] =
            f2bf(fmaxf(acc[f][r] * scale_s[c] + shift_s[c], 0.f));
      }
    __syncthreads();

    // coalesced store: lane (q,kg) stores row base+q, 16B chunks kg and kg+4
    int node_s = base + q;
    const uint4* hr4 = reinterpret_cast<const uint4*>(&hts[w * 16 + q][0]);
    uint4 s0 = hr4[kg];
    uint4 s1 = hr4[kg + 4];
    if (node_s < N_NODES) {
      uint4* gout = reinterpret_cast<uint4*>(h1h + (size_t)node_s * D);
      gout[kg] = s0;
      gout[kg + 4] = s1;
    }
    __syncthreads();
  }
}

// ---------------------------------------------------------------------------
// Layer 2 via MFMA + MFMA MLP head + sigmoid.
// h2 staged as bf16 in padded LDS tile; head z = h2 @ mW1^T via 4 MFMAs
// (M=16 nodes, N=32, K=64); relu+mW2 on accumulator; shfl-reduce; sigmoid.
// ---------------------------------------------------------------------------
__global__ __launch_bounds__(256) void layer2_mfma(
    const unsigned short* __restrict__ meanh, const unsigned short* __restrict__ h1h,
    const float* __restrict__ Wl, const float* __restrict__ bl,
    const float* __restrict__ Wr,
    const float* __restrict__ g, const float* __restrict__ beta,
    const float* __restrict__ m, const float* __restrict__ v,
    const float* __restrict__ mW1, const float* __restrict__ mb1,
    const float* __restrict__ mW2, const float* __restrict__ mb2,
    float* __restrict__ out) {
  __shared__ float scale_s[D];
  __shared__ float shift_s[D];
  __shared__ unsigned short hts[64][72];
  int tid = threadIdx.x;
  if (tid < D) {
    float s = g[tid] * rsqrtf(v[tid] + BN_EPS);
    scale_s[tid] = s;
    shift_s[tid] = (bl[tid] - m[tid]) * s + beta[tid];
  }
  __syncthreads();

  int w = tid >> 6, lane = tid & 63, q = lane & 15, kg = lane >> 4;

  bf16x8 b[4][4];
#pragma unroll
  for (int f = 0; f < 4; ++f) {
    int c = f * 16 + q;
    b[0][f] = ldw(Wl + c * D + kg * 8);
    b[1][f] = ldw(Wl + c * D + 32 + kg * 8);
    b[2][f] = ldw(Wr + c * D + kg * 8);
    b[3][f] = ldw(Wr + c * D + 32 + kg * 8);
  }
  // head B frags: bh[s][f] = mW1[f*16+q][s*32 + kg*8 .. +7]
  bf16x8 bh[2][2];
#pragma unroll
  for (int f = 0; f < 2; ++f)
#pragma unroll
    for (int s = 0; s < 2; ++s)
      bh[s][f] = ldw(mW1 + (f * 16 + q) * D + s * 32 + kg * 8);
  float mw2v0 = mW2[q], mw2v1 = mW2[16 + q];
  float mb1v0 = mb1[q], mb1v1 = mb1[16 + q];
  float mb2v = mb2[0];

#pragma unroll
  for (int mt = 0; mt < MT; ++mt) {
    int base = blockIdx.x * (64 * MT) + mt * 64 + w * 16;
    int nodeA = base + q;
    if (nodeA > N_NODES - 1) nodeA = N_NODES - 1;
    const unsigned short* mrow = meanh + (size_t)nodeA * D;
    const unsigned short* xrow = h1h + (size_t)nodeA * D;
    bf16x8 a0 = *reinterpret_cast<const bf16x8*>(mrow + kg * 8);
    bf16x8 a1 = *reinterpret_cast<const bf16x8*>(mrow + 32 + kg * 8);
    bf16x8 a2 = *reinterpret_cast<const bf16x8*>(xrow + kg * 8);
    bf16x8 a3 = *reinterpret_cast<const bf16x8*>(xrow + 32 + kg * 8);

    f32x4 acc[4];
#pragma unroll
    for (int f = 0; f < 4; ++f) {
      acc[f] = (f32x4){0.f, 0.f, 0.f, 0.f};
      acc[f] = __builtin_amdgcn_mfma_f32_16x16x32_bf16(a0, b[0][f], acc[f], 0, 0, 0);
      acc[f] = __builtin_amdgcn_mfma_f32_16x16x32_bf16(a1, b[1][f], acc[f], 0, 0, 0);
      acc[f] = __builtin_amdgcn_mfma_f32_16x16x32_bf16(a2, b[2][f], acc[f], 0, 0, 0);
      acc[f] = __builtin_amdgcn_mfma_f32_16x16x32_bf16(a3, b[3][f], acc[f], 0, 0, 0);
    }

    // BN + ReLU -> bf16 LDS tile
#pragma unroll
    for (int r = 0; r < 4; ++r)
#pragma unroll
      for (int f = 0; f < 4; ++f) {
        int c = f * 16 + q;
        hts[w * 16 + kg * 4 + r][c] =
            f2bf(fmaxf(acc[f][r] * scale_s[c] + shift_s[c], 0.f));
      }
    __syncthreads();

    // head GEMM: A = hts rows (own wave's 16 nodes), K=64 (2 steps)
    const unsigned short* hrow = &hts[w * 16 + q][0];
    bf16x8 ha0 = *reinterpret_cast<const bf16x8*>(hrow + kg * 8);
    bf16x8 ha1 = *reinterpret_cast<const bf16x8*>(hrow + 32 + kg * 8);
    f32x4 az0 = (f32x4){0.f, 0.f, 0.f, 0.f};
    f32x4 az1 = (f32x4){0.f, 0.f, 0.f, 0.f};
    az0 = __builtin_amdgcn_mfma_f32_16x16x32_bf16(ha0, bh[0][0], az0, 0, 0, 0);
    az0 = __builtin_amdgcn_mfma_f32_16x16x32_bf16(ha1, bh[1][0], az0, 0, 0, 0);
    az1 = __builtin_amdgcn_mfma_f32_16x16x32_bf16(ha0, bh[0][1], az1, 0, 0, 0);
    az1 = __builtin_amdgcn_mfma_f32_16x16x32_bf16(ha1, bh[1][1], az1, 0, 0, 0);

    // per-lane: relu(z + mb1) * mW2, then reduce over the 16 q-lanes
    float ps[4];
#pragma unroll
    for (int r = 0; r < 4; ++r)
      ps[r] = fmaxf(az0[r] + mb1v0, 0.f) * mw2v0 +
              fmaxf(az1[r] + mb1v1, 0.f) * mw2v1;
#pragma unroll
    for (int d = 1; d <= 8; d <<= 1) {
      ps[0] += __shfl_xor(ps[0], d);
      ps[1] += __shfl_xor(ps[1], d);
      ps[2] += __shfl_xor(ps[2], d);
      ps[3] += __shfl_xor(ps[3], d);
    }
    if (q == 0) {
#pragma unroll
      for (int r = 0; r < 4; ++r) {
        int node = base + kg * 4 + r;
        if (node < N_NODES)
          out[node] = 1.0f / (1.0f + expf(-(ps[r] + mb2v)));
      }
    }
    __syncthreads();
  }
}

// ---------------------------------------------------------------------------
extern "C" void kernel_launch(void* const* d_in, const int* in_sizes, int n_in,
                              void* d_out, int out_size, void* d_ws, size_t ws_size,
                              hipStream_t stream) {
  const float* x    = (const float*)d_in[0];
  const int*   ei   = (const int*)d_in[1];
  const float* Wl1  = (const float*)d_in[2];
  const float* bl1  = (const float*)d_in[3];
  const float* Wr1  = (const float*)d_in[4];
  const float* g1   = (const float*)d_in[5];
  const float* be1  = (const float*)d_in[6];
  const float* m1   = (const float*)d_in[7];
  const float* v1   = (const float*)d_in[8];
  const float* Wl2  = (const float*)d_in[9];
  const float* bl2  = (const float*)d_in[10];
  const float* Wr2  = (const float*)d_in[11];
  const float* g2   = (const float*)d_in[12];
  const float* be2  = (const float*)d_in[13];
  const float* m2   = (const float*)d_in[14];
  const float* v2   = (const float*)d_in[15];
  const float* mW1  = (const float*)d_in[16];
  const float* mb1  = (const float*)d_in[17];
  const float* mW2  = (const float*)d_in[18];
  const float* mb2  = (const float*)d_in[19];
  float* out = (float*)d_out;

  const int* src = ei;
  const int* dst = ei + NE;

  // ws layout (no memsets; everything written before read):
  //   meanh | xh | h1h (bf16 N*D each) | ebuk (NE int, packed) | col (NE int)
  //   | row_start (N+16) | bhist (NSCAN) | bsum (512)
  unsigned short* meanh = (unsigned short*)d_ws;
  unsigned short* xh    = meanh + (size_t)N_NODES * D;
  unsigned short* h1h   = xh + (size_t)N_NODES * D;
  int* ebuk      = (int*)(h1h + (size_t)N_NODES * D);
  int* col       = ebuk + NE;
  int* row_start = col + NE;
  int* bhist     = row_start + (N_NODES + 16);
  int* bsum      = bhist + NSCAN;

  const int scan_blocks = NSCAN / SCAN_B;                    // 256
  const int agg_blocks  = (N_NODES + 15) / 16;
  const int gemm_blocks = (N_NODES + 64 * MT - 1) / (64 * MT);

  // --- CSR build (LDS bucket counting sort, zero global atomics) ---
  bucket_hist_kernel<<<NB1, 256, 0, stream>>>(dst, bhist, x, xh);
  scan_part<<<scan_blocks, SCAN_B, 0, stream>>>(bhist, bsum, NSCAN);
  scan_mid<<<1, 256, 0, stream>>>(bsum, scan_blocks);
  scan_add<<<scan_blocks, SCAN_B, 0, stream>>>(bhist, bsum, NSCAN);
  bucket_scatter_kernel<<<NB1, 256, 0, stream>>>(src, dst, bhist, ebuk);
  bucket_csr_kernel<<<NBUK_USED, 512, 0, stream>>>(ebuk, bhist, row_start, col);

  // --- layer 1 ---
  aggregate_kernel<<<agg_blocks, 256, 0, stream>>>(xh, row_start, col, meanh);
  layer1_mfma<<<gemm_blocks, 256, 0, stream>>>(meanh, xh, Wl1, bl1, Wr1,
                                               g1, be1, m1, v1, h1h);
  // --- layer 2 ---
  aggregate_kernel<<<agg_blocks, 256, 0, stream>>>(h1h, row_start, col, meanh);
  layer2_mfma<<<gemm_blocks, 256, 0, stream>>>(meanh, h1h, Wl2, bl2, Wr2,
                                               g2, be2, m2, v2,
                                               mW1, mb1, mW2, mb2, out);
}